// Round 5
// baseline (97.340 us; speedup 1.0000x reference)
//
#include <hip/hip_runtime.h>
#include <hip/hip_bf16.h>

#define EPS 0.3f

typedef float vf4 __attribute__((ext_vector_type(4)));

__device__ __forceinline__ float eps_fix(float x) {
    return (fabsf(x) < EPS) ? ((x < 0.0f) ? -EPS : EPS) : x;
}

__device__ __forceinline__ vf4 eps_fix4(vf4 v) {
    vf4 r;
    r.x = eps_fix(v.x);
    r.y = eps_fix(v.y);
    r.z = eps_fix(v.z);
    r.w = eps_fix(v.w);
    return r;
}

// 2 float4 per thread: two coalesced 256-wide segments per block.
// Dense linear sweep, 32 B in flight per thread.
__global__ void eps_clamp_kernel(const vf4* __restrict__ in,
                                 vf4* __restrict__ out,
                                 int n4) {
    int base = blockIdx.x * (blockDim.x * 2) + threadIdx.x;
    int i0 = base;
    int i1 = base + blockDim.x;
    if (i1 < n4) {
        vf4 v0 = in[i0];
        vf4 v1 = in[i1];
        out[i0] = eps_fix4(v0);
        out[i1] = eps_fix4(v1);
    } else if (i0 < n4) {
        out[i0] = eps_fix4(in[i0]);
    }
}

extern "C" void kernel_launch(void* const* d_in, const int* in_sizes, int n_in,
                              void* d_out, int out_size, void* d_ws, size_t ws_size,
                              hipStream_t stream) {
    const float* x = (const float*)d_in[0];
    float* out = (float*)d_out;
    int n = in_sizes[0];          // 8192*8192 = 67108864, divisible by 4
    int n4 = n / 4;               // 16777216 float4s

    const int block = 256;
    const int per_block = block * 2;                 // 512 float4s per block
    int grid = (n4 + per_block - 1) / per_block;     // 32768 blocks

    eps_clamp_kernel<<<grid, block, 0, stream>>>(
        (const vf4*)x, (vf4*)out, n4);
}

// Round 6
// 77.576 us; speedup vs baseline: 1.2548x; 1.2548x over previous
//
#include <hip/hip_runtime.h>
#include <hip/hip_bf16.h>

#define EPS 0.3f

typedef float vf4 __attribute__((ext_vector_type(4)));

__device__ __forceinline__ float eps_fix(float x) {
    return (fabsf(x) < EPS) ? ((x < 0.0f) ? -EPS : EPS) : x;
}

// One float4 per thread, dense linear sweep (round-4 shape, best so far).
// Cached loads; NON-TEMPORAL stores (zero-reuse write stream, full-line).
__global__ void eps_clamp_kernel(const vf4* __restrict__ in,
                                 vf4* __restrict__ out,
                                 int n4) {
    int tid = blockIdx.x * blockDim.x + threadIdx.x;
    if (tid < n4) {
        vf4 v = in[tid];
        vf4 r;
        r.x = eps_fix(v.x);
        r.y = eps_fix(v.y);
        r.z = eps_fix(v.z);
        r.w = eps_fix(v.w);
        __builtin_nontemporal_store(r, &out[tid]);
    }
}

extern "C" void kernel_launch(void* const* d_in, const int* in_sizes, int n_in,
                              void* d_out, int out_size, void* d_ws, size_t ws_size,
                              hipStream_t stream) {
    const float* x = (const float*)d_in[0];
    float* out = (float*)d_out;
    int n = in_sizes[0];          // 8192*8192 = 67108864, divisible by 4
    int n4 = n / 4;

    const int block = 256;
    int grid = (n4 + block - 1) / block;   // 65536 blocks, one float4/thread

    eps_clamp_kernel<<<grid, block, 0, stream>>>(
        (const vf4*)x, (vf4*)out, n4);
}